// Round 1
// baseline (83.857 us; speedup 1.0000x reference)
//
#include <hip/hip_runtime.h>
#include <math.h>

#define NB 2
#define NN 768
#define ND 64
#define XSTRIDE 68   // floats; 272 B rows: 16B-aligned writes, conflict-free reads
#define CH 32        // pairs staged per wave per chunk (per-wave LDS slab)

// barrier'd f32 ops: block FMA contraction / reassociation so rounding
// matches the numpy f32 reference bit-for-bit on sensitive chains
__device__ __forceinline__ float fmul_(float a, float b) { float r = a * b; asm volatile("" : "+v"(r)); return r; }
__device__ __forceinline__ float fadd_(float a, float b) { float r = a + b; asm volatile("" : "+v"(r)); return r; }

// numpy pairwise_sum for n=64 over a per-lane register array:
// 8 accumulators striding 8, then ((r0+r1)+(r2+r3)) + ((r4+r5)+(r6+r7))
template <typename F>
__device__ __forceinline__ float pw64(F f) {
  float r[8];
#pragma unroll
  for (int m = 0; m < 8; ++m) r[m] = f(m);
#pragma unroll
  for (int i = 1; i < 8; ++i) {
#pragma unroll
    for (int m = 0; m < 8; ++m) r[m] = fadd_(r[m], f(8 * i + m));
  }
  const float s01 = fadd_(r[0], r[1]), s23 = fadd_(r[2], r[3]);
  const float s45 = fadd_(r[4], r[5]), s67 = fadd_(r[6], r[7]);
  return fadd_(fadd_(s01, s23), fadd_(s45, s67));
}

// shuffle-based pairwise sum over lane-distributed values (lane k holds v_k).
// Bitwise-identical to pw64 (stage-1 same order; butterfly = balanced tree up
// to fp-add commutativity, which preserves rounding).
__device__ __forceinline__ float pwShfl(float v, int lane) {
  const int m = lane & 7;
  float s = __shfl(v, m);
#pragma unroll
  for (int i = 1; i < 8; ++i) s = fadd_(s, __shfl(v, m + 8 * i));
  s = fadd_(s, __shfl_xor(s, 1));
  s = fadd_(s, __shfl_xor(s, 2));
  s = fadd_(s, __shfl_xor(s, 4));
  return s;
}

// two independent pairwise sums, interleaved so the serial shuffle chains
// overlap; each result bitwise-identical to pwShfl of that input alone
__device__ __forceinline__ void pwShfl2(float va, float vb, int lane,
                                        float& sa, float& sb) {
  const int m = lane & 7;
  float a = __shfl(va, m), b = __shfl(vb, m);
#pragma unroll
  for (int i = 1; i < 8; ++i) {
    a = fadd_(a, __shfl(va, m + 8 * i));
    b = fadd_(b, __shfl(vb, m + 8 * i));
  }
  a = fadd_(a, __shfl_xor(a, 1)); b = fadd_(b, __shfl_xor(b, 1));
  a = fadd_(a, __shfl_xor(a, 2)); b = fadd_(b, __shfl_xor(b, 2));
  a = fadd_(a, __shfl_xor(a, 4)); b = fadd_(b, __shfl_xor(b, 4));
  sa = a; sb = b;
}

// correctly-rounded n/d given r = fl(1/d) (Markstein refinement; benign range)
__device__ __forceinline__ float div_rn(float n, float d, float r) {
  const float q0 = n * r;
  const float e  = __builtin_fmaf(-d, q0, n);
  return __builtin_fmaf(e, r, q0);
}

// TWO waves per row (128-thread block): wave 0 owns quarters {0,1} = pairs
// [0,qb2), wave 1 owns quarters {2,3} = pairs [qb2,count). Each wave runs the
// full bit-faithful per-pair Phase A chain for its pairs and its own two
// ascending-p Q chains (order identical to the 1-wave kernel). Cross-wave
// combine is exactly (Q0+Q1)+(Q2+Q3); only P's lane/wave partition changes
// (reorder noise ~1e-7, not on the atanh-amplified path). Both waves compute
// compaction redundantly (same-value LDS writes: benign). Each wave has a
// private lds_x/cf_s slab -> no barriers in the main loop; single barrier at
// the Q/P handoff. 1536 blocks x 2 waves = 3072 waves = 3/SIMD, all resident.
__global__ __launch_bounds__(128, 3) void k_main(const float* __restrict__ x,
                                                 const float* __restrict__ adj,
                                                 const float* __restrict__ attW,
                                                 const float* __restrict__ attb,
                                                 float* __restrict__ out) {
  __shared__ float xi_s[ND];
  __shared__ float sW2[ND];
  __shared__ short lj[NN];
  __shared__ float cf_s[2][CH];
  __shared__ float lds_x[2][CH * XSTRIDE];
  __shared__ float qbuf[ND];
  __shared__ float pbuf[ND];

  const int row  = blockIdx.x;           // 0..1535 = b*NN + i
  const int b    = row / NN;
  const int tid  = threadIdx.x;          // 0..127
  const int wv   = tid >> 6;             // wave id 0/1
  const int lane = tid & 63;

  const float xiv = x[(size_t)row * ND + lane];
  xi_s[lane] = xiv;                      // both waves write identical values
  sW2[lane]  = attW[ND + lane];

  // hoist adjacency chunk loads (independent; overlap with n_i computation)
  const float* __restrict__ arow = adj + (size_t)row * NN;
  float av[NN / 64];
#pragma unroll
  for (int c = 0; c < NN / 64; ++c) av[c] = arow[c * 64 + lane];

  // n_i with numpy-pairwise rounding (bitwise same as before)
  const float ni = pwShfl(fmul_(xiv, xiv), lane);

  const float b1  = 1.0f - ni;                       // Sterbenz: exact
  const float lam = 2.0f / fmaxf(b1, 1e-15f);        // ref rounding
  const float g1  = 2.0f / lam;                      // double-rounded "2/lam"
  const float ab  = attb[0];
  const float ATH_CLIP = (float)(1.0 - 1e-07);

  // ---- compact nonzero adj columns, ascending j; record quarter bounds ----
  // both waves compute identical lj redundantly (same-value writes: benign)
  int count = 0, qb1 = 0, qb2 = 0, qb3 = 0;
#pragma unroll
  for (int c = 0; c < NN / 64; ++c) {
    const unsigned long long m = __ballot(av[c] != 0.0f);
    if (av[c] != 0.0f) {
      const int rank = __popcll(m & ((1ull << lane) - 1ull));
      lj[count + rank] = (short)(c * 64 + lane);
    }
    count += __popcll(m);                // wave-uniform
    if (c == 2) qb1 = count;             // end of j<192
    if (c == 5) qb2 = count;             // end of j<384
    if (c == 8) qb3 = count;             // end of j<576
  }
  // no barrier: each wave wrote the entire lj it reads

  const float* __restrict__ xb = x + (size_t)b * NN * ND;
  const int myLo = wv ? qb2 : 0;         // this wave's pair range
  const int myHi = wv ? count : qb2;
  const int qMid = wv ? qb3 : qb1;       // boundary between its two quarters

  float pP = 0.0f;
  float Qa = 0.0f, Qb = 0.0f;            // this wave's two quarter chains

  for (int base = myLo; base < myHi; base += CH) {
    const int valid = min(myHi - base, CH);

    // ---- Phase A: per-pair chain (bitwise identical to previous rounds) ----
    if (lane < valid) {
      const int j = lj[base + lane];
      float rj[ND];
      const float4* __restrict__ xj4 = (const float4*)(xb + (size_t)j * ND);
#pragma unroll
      for (int k4 = 0; k4 < 16; ++k4) {
        const float4 v = xj4[k4];
        rj[4 * k4 + 0] = v.x; rj[4 * k4 + 1] = v.y;
        rj[4 * k4 + 2] = v.z; rj[4 * k4 + 3] = v.w;
      }
      // stage row into this wave's private LDS slab for Phase B
      {
        float4* __restrict__ dst = (float4*)&lds_x[wv][lane * XSTRIDE];
#pragma unroll
        for (int k4 = 0; k4 < 16; ++k4)
          dst[k4] = make_float4(rj[4 * k4], rj[4 * k4 + 1],
                                rj[4 * k4 + 2], rj[4 * k4 + 3]);
      }
      const float nj = pw64([&](int k) { return fmul_(rj[k], rj[k]); });
      const float d  = pw64([&](int k) { return fmul_(xi_s[k], rj[k]); });
      const float xy = -d;
      const float t1  = fadd_(1.0f, 2.0f * xy);      // 2*xy exact
      const float a1  = fadd_(t1, nj);               // 1 + 2c*xy + c*y2
      const float den = fadd_(t1, fmul_(ni, nj));    // 1 + 2c*xy + c^2*x2*y2
      const float denc = fmaxf(den, 1e-15f);
      const float rden = 1.0f / denc;
      float racc[8];
      float subW = 0.0f;
#pragma unroll
      for (int m = 0; m < 8; ++m) {
        const float nk = fadd_(-fmul_(a1, xi_s[m]), fmul_(b1, rj[m]));
        const float sk = div_rn(nk, denc, rden);
        subW = __builtin_fmaf(sk, sW2[m], subW);
        racc[m] = fmul_(sk, sk);
      }
#pragma unroll
      for (int i8 = 1; i8 < 8; ++i8) {
#pragma unroll
        for (int m = 0; m < 8; ++m) {
          const int k = 8 * i8 + m;
          const float nk = fadd_(-fmul_(a1, xi_s[k]), fmul_(b1, rj[k]));
          const float sk = div_rn(nk, denc, rden);
          subW = __builtin_fmaf(sk, sW2[k], subW);
          racc[m] = fadd_(racc[m], fmul_(sk, sk));
        }
      }
      const float s01 = fadd_(racc[0], racc[1]), s23 = fadd_(racc[2], racc[3]);
      const float s45 = fadd_(racc[4], racc[5]), s67 = fadd_(racc[6], racc[7]);
      const float s2  = fadd_(fadd_(s01, s23), fadd_(s45, s67));
      const float t   = sqrtf(s2);
      const float sn  = fmaxf(t, 1e-15f);            // sub_norm
      const float z   = fminf(sn, ATH_CLIP);
      const float ath = atanhf(z);
      const float g2  = fmul_(g1, ath);              // fl((2/lam)*artanh)
      const float gg  = g2 / sn;
      const float logit = gg * subW + ab;
      const float sig   = 1.0f / (1.0f + expf(-logit));
      const float cfac  = sig * gg * rden;           // att = sig*1.0 exactly
      cf_s[wv][lane] = cfac;                         // broadcast via LDS
      pP = __builtin_fmaf(cfac, a1, pP);             // P = sum coeff*A
    }
    // wave-local write->read on cf_s/lds_x: compiler-inserted lgkm waits;
    // no __syncthreads needed (private slab per wave)

    // ---- Phase B: this wave's two quarter chains, ascending p, 1-deep
    //      software prefetch (loads of p+1 overlap the dependent FMA) ----
    const int lim = base + valid;
    {
      const int lo = base, hi = min(qMid, lim);      // first owned quarter
      int p = lo;
      if (p < hi) {
        float c0 = cf_s[wv][p - base];
        float v0 = lds_x[wv][(p - base) * XSTRIDE + lane];
        while (++p < hi) {
          const float c1 = cf_s[wv][p - base];
          const float v1 = lds_x[wv][(p - base) * XSTRIDE + lane];
          Qa = __builtin_fmaf(c0, v0, Qa);
          c0 = c1; v0 = v1;
        }
        Qa = __builtin_fmaf(c0, v0, Qa);
      }
    }
    {
      const int lo = max(qMid, base), hi = lim;      // second owned quarter
      int p = lo;
      if (p < hi) {
        float c0 = cf_s[wv][p - base];
        float v0 = lds_x[wv][(p - base) * XSTRIDE + lane];
        while (++p < hi) {
          const float c1 = cf_s[wv][p - base];
          const float v1 = lds_x[wv][(p - base) * XSTRIDE + lane];
          Qb = __builtin_fmaf(c0, v0, Qb);
          c0 = c1; v0 = v1;
        }
        Qb = __builtin_fmaf(c0, v0, Qb);
      }
    }
  }

  // ---- cross-wave combine: Q = (Q0+Q1)+(Q2+Q3) exactly as before ----
  if (wv == 1) {
    qbuf[lane] = fadd_(Qa, Qb);          // Q2+Q3 (bitwise same inner order)
    pbuf[lane] = pP;
  }
  __syncthreads();
  if (wv == 0) {
    const float Q = fadd_(fadd_(Qa, Qb), qbuf[lane]);

    // wave-reduce P (scalar; reorder noise ~1e-7, not amplified)
    float pw = pP + pbuf[lane];
#pragma unroll
    for (int m = 32; m >= 1; m >>= 1) pw += __shfl_xor(pw, m, 64);
    const float P = pw;

    // ---- epilogue: expmap + mobius + proj (same ops; shuffle reductions) ----
    float u = b1 * Q - P * xiv;                      // support_t
    u = fminf(fmaxf(u, -1e6f), 1e6f);                // clip
    const float u2 = pwShfl(fmul_(u, u), lane);
    const float un = fmaxf(sqrtf(u2), 1e-15f);
    const float th = tanhf(fmul_(0.5f * lam, un));   // 0.5*lam exact
    const float sec = fmul_(th, u) / un;             // second_d
    float y2, xys;
    pwShfl2(fmul_(sec, sec), fmul_(xiv, sec), lane, y2, xys);
    const float t1e  = fadd_(1.0f, 2.0f * xys);
    const float a1e  = fadd_(t1e, y2);
    const float dene = fmaxf(fadd_(t1e, fmul_(ni, y2)), 1e-15f);
    const float o    = fadd_(fmul_(a1e, xiv), fmul_(b1, sec)) / dene;
    const float o2 = pwShfl(fmul_(o, o), lane);
    const float nm = fmaxf(sqrtf(o2), 1e-15f);
    const float res = (nm > 0.996f) ? fmul_(o / nm, 0.996f) : o;
    out[(size_t)row * ND + lane] = res;
  }
}

extern "C" void kernel_launch(void* const* d_in, const int* in_sizes, int n_in,
                              void* d_out, int out_size, void* d_ws, size_t ws_size,
                              hipStream_t stream) {
  const float* x    = (const float*)d_in[0];
  const float* adj  = (const float*)d_in[1];
  const float* attW = (const float*)d_in[2];
  const float* attb = (const float*)d_in[3];
  float* out = (float*)d_out;

  hipLaunchKernelGGL(k_main, dim3(NB * NN), dim3(128), 0, stream,
                     x, adj, attW, attb, out);
}

// Round 2
// 74.893 us; speedup vs baseline: 1.1197x; 1.1197x over previous
//
#include <hip/hip_runtime.h>
#include <math.h>

#define NB 2
#define NN 768
#define ND 64
#define XSTRIDE 68   // floats; 272 B rows: 16B-aligned writes, conflict-free reads

// barrier'd f32 ops: block FMA contraction / reassociation so rounding
// matches the numpy f32 reference bit-for-bit on sensitive chains
__device__ __forceinline__ float fmul_(float a, float b) { float r = a * b; asm volatile("" : "+v"(r)); return r; }
__device__ __forceinline__ float fadd_(float a, float b) { float r = a + b; asm volatile("" : "+v"(r)); return r; }

// numpy pairwise_sum for n=64 over a per-lane register array:
// 8 accumulators striding 8, then ((r0+r1)+(r2+r3)) + ((r4+r5)+(r6+r7))
template <typename F>
__device__ __forceinline__ float pw64(F f) {
  float r[8];
#pragma unroll
  for (int m = 0; m < 8; ++m) r[m] = f(m);
#pragma unroll
  for (int i = 1; i < 8; ++i) {
#pragma unroll
    for (int m = 0; m < 8; ++m) r[m] = fadd_(r[m], f(8 * i + m));
  }
  const float s01 = fadd_(r[0], r[1]), s23 = fadd_(r[2], r[3]);
  const float s45 = fadd_(r[4], r[5]), s67 = fadd_(r[6], r[7]);
  return fadd_(fadd_(s01, s23), fadd_(s45, s67));
}

// shuffle-based pairwise sum, bitwise-identical to pw64 — used ONLY for ni,
// which sits on the atanh-amplified path and must match numpy exactly.
__device__ __forceinline__ float pwShfl(float v, int lane) {
  const int m = lane & 7;
  float s = __shfl(v, m);
#pragma unroll
  for (int i = 1; i < 8; ++i) s = fadd_(s, __shfl(v, m + 8 * i));
  s = fadd_(s, __shfl_xor(s, 1));
  s = fadd_(s, __shfl_xor(s, 2));
  s = fadd_(s, __shfl_xor(s, 4));
  return s;
}

// 6-step xor butterfly for the epilogue sums (u2, y2, xys, o2). These are
// POST-atanh (non-amplified): reorder vs numpy-pairwise is ~1e-7 relative,
// ~4 orders under the absmax margin. 6 serial shuffles instead of 11.
__device__ __forceinline__ float bfly(float v) {
  v = fadd_(v, __shfl_xor(v, 1));
  v = fadd_(v, __shfl_xor(v, 2));
  v = fadd_(v, __shfl_xor(v, 4));
  v = fadd_(v, __shfl_xor(v, 8));
  v = fadd_(v, __shfl_xor(v, 16));
  v = fadd_(v, __shfl_xor(v, 32));
  return v;
}

// correctly-rounded n/d given r = fl(1/d) (Markstein refinement; benign range)
__device__ __forceinline__ float div_rn(float n, float d, float r) {
  const float q0 = n * r;
  const float e  = __builtin_fmaf(-d, q0, n);
  return __builtin_fmaf(e, r, q0);
}

// One wave per row (round-0 structure: 2-wave split refuted in round 1 —
// Phase A is a single lane-parallel pass at count~38, so splitting only
// duplicated issue and spilled under the (128,3) VGPR cap).
// Round-2 deltas: Phase B depth-4 LDS prefetch (same bitwise FMA chains),
// subW 8-way chains (logit reorder ~1e-7), epilogue xor-butterflies.
__global__ __launch_bounds__(64) void k_main(const float* __restrict__ x,
                                             const float* __restrict__ adj,
                                             const float* __restrict__ attW,
                                             const float* __restrict__ attb,
                                             float* __restrict__ out) {
  __shared__ float xi_s[ND];
  __shared__ float sW2[ND];
  __shared__ short lj[NN];
  __shared__ float cf_s[64];
  __shared__ float lds_x[64 * XSTRIDE];

  const int row  = blockIdx.x;           // 0..1535 = b*NN + i
  const int b    = row / NN;
  const int lane = threadIdx.x;          // 0..63

  const float xiv = x[(size_t)row * ND + lane];
  xi_s[lane] = xiv;
  sW2[lane]  = attW[ND + lane];

  // hoist adjacency chunk loads (independent; overlap with n_i computation)
  const float* __restrict__ arow = adj + (size_t)row * NN;
  float av[NN / 64];
#pragma unroll
  for (int c = 0; c < NN / 64; ++c) av[c] = arow[c * 64 + lane];

  // n_i with numpy-pairwise rounding (on the amplified path: keep EXACT)
  const float ni = pwShfl(fmul_(xiv, xiv), lane);

  const float b1  = 1.0f - ni;                       // Sterbenz: exact
  const float lam = 2.0f / fmaxf(b1, 1e-15f);        // ref rounding
  const float g1  = 2.0f / lam;                      // double-rounded "2/lam"
  const float ab  = attb[0];
  const float ATH_CLIP = (float)(1.0 - 1e-07);

  // ---- compact nonzero adj columns, ascending j; record quarter bounds ----
  int count = 0, qb1 = 0, qb2 = 0, qb3 = 0;
#pragma unroll
  for (int c = 0; c < NN / 64; ++c) {
    const unsigned long long m = __ballot(av[c] != 0.0f);
    if (av[c] != 0.0f) {
      const int rank = __popcll(m & ((1ull << lane) - 1ull));
      lj[count + rank] = (short)(c * 64 + lane);
    }
    count += __popcll(m);                // wave-uniform
    if (c == 2) qb1 = count;             // end of j<192
    if (c == 5) qb2 = count;             // end of j<384
    if (c == 8) qb3 = count;             // end of j<576
  }
  __syncthreads();

  const float* __restrict__ xb = x + (size_t)b * NN * ND;
  float pP = 0.0f;
  float Q0 = 0.0f, Q1 = 0.0f, Q2 = 0.0f, Q3 = 0.0f;

  for (int base = 0; base < count; base += 64) {
    const int valid = min(count - base, 64);

    // ---- Phase A: per-pair chain (sk/racc bitwise identical to round 0) ----
    if (lane < valid) {
      const int j = lj[base + lane];
      float rj[ND];
      const float4* __restrict__ xj4 = (const float4*)(xb + (size_t)j * ND);
#pragma unroll
      for (int k4 = 0; k4 < 16; ++k4) {
        const float4 v = xj4[k4];
        rj[4 * k4 + 0] = v.x; rj[4 * k4 + 1] = v.y;
        rj[4 * k4 + 2] = v.z; rj[4 * k4 + 3] = v.w;
      }
      // stage row into LDS for Phase B (values only; layout free)
      {
        float4* __restrict__ dst = (float4*)&lds_x[lane * XSTRIDE];
#pragma unroll
        for (int k4 = 0; k4 < 16; ++k4)
          dst[k4] = make_float4(rj[4 * k4], rj[4 * k4 + 1],
                                rj[4 * k4 + 2], rj[4 * k4 + 3]);
      }
      const float nj = pw64([&](int k) { return fmul_(rj[k], rj[k]); });
      const float d  = pw64([&](int k) { return fmul_(xi_s[k], rj[k]); });
      const float xy = -d;
      const float t1  = fadd_(1.0f, 2.0f * xy);      // 2*xy exact
      const float a1  = fadd_(t1, nj);               // 1 + 2c*xy + c*y2
      const float den = fadd_(t1, fmul_(ni, nj));    // 1 + 2c*xy + c^2*x2*y2
      const float denc = fmaxf(den, 1e-15f);
      const float rden = 1.0f / denc;
      float racc[8];
      float sw[8];                      // subW: 8 parallel chains (was serial)
#pragma unroll
      for (int m = 0; m < 8; ++m) {
        const float nk = fadd_(-fmul_(a1, xi_s[m]), fmul_(b1, rj[m]));
        const float sk = div_rn(nk, denc, rden);
        sw[m]   = __builtin_fmaf(sk, sW2[m], 0.0f);  // == rounded sk*W2
        racc[m] = fmul_(sk, sk);
      }
#pragma unroll
      for (int i8 = 1; i8 < 8; ++i8) {
#pragma unroll
        for (int m = 0; m < 8; ++m) {
          const int k = 8 * i8 + m;
          const float nk = fadd_(-fmul_(a1, xi_s[k]), fmul_(b1, rj[k]));
          const float sk = div_rn(nk, denc, rden);
          sw[m]   = __builtin_fmaf(sk, sW2[k], sw[m]);
          racc[m] = fadd_(racc[m], fmul_(sk, sk));
        }
      }
      const float s01 = fadd_(racc[0], racc[1]), s23 = fadd_(racc[2], racc[3]);
      const float s45 = fadd_(racc[4], racc[5]), s67 = fadd_(racc[6], racc[7]);
      const float s2  = fadd_(fadd_(s01, s23), fadd_(s45, s67));
      const float w01 = fadd_(sw[0], sw[1]), w23 = fadd_(sw[2], sw[3]);
      const float w45 = fadd_(sw[4], sw[5]), w67 = fadd_(sw[6], sw[7]);
      const float subW = fadd_(fadd_(w01, w23), fadd_(w45, w67));
      const float t   = sqrtf(s2);
      const float sn  = fmaxf(t, 1e-15f);            // sub_norm
      const float z   = fminf(sn, ATH_CLIP);
      const float ath = atanhf(z);
      const float g2  = fmul_(g1, ath);              // fl((2/lam)*artanh)
      const float gg  = g2 / sn;
      const float logit = gg * subW + ab;
      const float sig   = 1.0f / (1.0f + expf(-logit));
      const float cfac  = sig * gg * rden;           // att = sig*1.0 exactly
      cf_s[lane] = cfac;                             // broadcast via LDS
      pP = __builtin_fmaf(cfac, a1, pP);             // P = sum coeff*A
    }
    // wave-local LDS write->read (cf_s, lds_x): in-wave DS ordering +
    // compiler lgkm waits — same contract round-0 relied on for lds_x.

    // ---- Phase B: four ascending-p quarter chains (bitwise identical to
    //      round 0) with depth-4 rotating prefetch: LDS latency hidden. ----
    const int lim = base + valid;
    auto qloop = [&](int lo, int hi, float& Q) {
      if (lo >= hi) return;
      const int last = hi - 1 - base;                // clamp target (valid row)
      const int i0 = lo - base;
      const int i1 = min(i0 + 1, last);
      const int i2 = min(i0 + 2, last);
      const int i3 = min(i0 + 3, last);
      float c0 = cf_s[i0], v0 = lds_x[i0 * XSTRIDE + lane];
      float c1 = cf_s[i1], v1 = lds_x[i1 * XSTRIDE + lane];
      float c2 = cf_s[i2], v2 = lds_x[i2 * XSTRIDE + lane];
      float c3 = cf_s[i3], v3 = lds_x[i3 * XSTRIDE + lane];
#pragma unroll 4
      for (int p = lo; p < hi; ++p) {
        const int in = min(p - base + 4, last);      // over-prefetch clamped:
        const float cn = cf_s[in];                   // loaded, never consumed
        const float vn = lds_x[in * XSTRIDE + lane];
        Q = __builtin_fmaf(c0, v0, Q);               // exact round-0 chain
        c0 = c1; v0 = v1; c1 = c2; v1 = v2; c2 = c3; v2 = v3; c3 = cn; v3 = vn;
      }
    };
    qloop(base,           min(qb1, lim),   Q0);
    qloop(max(qb1, base), min(qb2, lim),   Q1);
    qloop(max(qb2, base), min(qb3, lim),   Q2);
    qloop(max(qb3, base), min(count, lim), Q3);
    __syncthreads();                                 // before re-staging
  }

  // wave-reduce P (scalar; reorder noise ~1e-7, not amplified)
  float pw = pP;
#pragma unroll
  for (int m = 32; m >= 1; m >>= 1) pw += __shfl_xor(pw, m, 64);
  const float P = pw;
  const float Q = (Q0 + Q1) + (Q2 + Q3);

  // ---- epilogue: expmap + mobius + proj (butterfly reductions; sums are
  //      post-atanh so the ~1e-7 reorder is far under the absmax margin) ----
  float u = b1 * Q - P * xiv;                        // support_t
  u = fminf(fmaxf(u, -1e6f), 1e6f);                  // clip
  const float u2 = bfly(fmul_(u, u));
  const float un = fmaxf(sqrtf(u2), 1e-15f);
  const float th = tanhf(fmul_(0.5f * lam, un));     // 0.5*lam exact
  const float sec = fmul_(th, u) / un;               // second_d
  const float y2  = bfly(fmul_(sec, sec));
  const float xys = bfly(fmul_(xiv, sec));
  const float t1e  = fadd_(1.0f, 2.0f * xys);
  const float a1e  = fadd_(t1e, y2);
  const float dene = fmaxf(fadd_(t1e, fmul_(ni, y2)), 1e-15f);
  const float o    = fadd_(fmul_(a1e, xiv), fmul_(b1, sec)) / dene;
  const float o2 = bfly(fmul_(o, o));
  const float nm = fmaxf(sqrtf(o2), 1e-15f);
  const float res = (nm > 0.996f) ? fmul_(o / nm, 0.996f) : o;
  out[(size_t)row * ND + lane] = res;
}

extern "C" void kernel_launch(void* const* d_in, const int* in_sizes, int n_in,
                              void* d_out, int out_size, void* d_ws, size_t ws_size,
                              hipStream_t stream) {
  const float* x    = (const float*)d_in[0];
  const float* adj  = (const float*)d_in[1];
  const float* attW = (const float*)d_in[2];
  const float* attb = (const float*)d_in[3];
  float* out = (float*)d_out;

  hipLaunchKernelGGL(k_main, dim3(NB * NN), dim3(64), 0, stream,
                     x, adj, attW, attb, out);
}